// Round 11
// baseline (329.593 us; speedup 1.0000x reference)
//
#include <hip/hip_runtime.h>
#include <hip/hip_bf16.h>
#include <math.h>

#define SEQ 2048
#define HID 1024
#define NH 16
#define HD 64

using f32x4   = __attribute__((ext_vector_type(4))) float;
using f32x16  = __attribute__((ext_vector_type(16))) float;
using bf16x8  = __attribute__((ext_vector_type(8))) short;

union U8 { unsigned int u[4]; bf16x8 v; short s[8]; };

__device__ __forceinline__ short f2bf(float f) {
  unsigned int x = __float_as_uint(f);
  unsigned int r = (x + 0x7fffu + ((x >> 16) & 1u)) >> 16;
  return (short)(r & 0xffffu);
}

__device__ __forceinline__ unsigned int pkbf(float a, float b) {
  return ((unsigned int)(unsigned short)f2bf(a)) |
         (((unsigned int)(unsigned short)f2bf(b)) << 16);
}

__device__ __forceinline__ float bf2f_lo(unsigned int u) {
  return __uint_as_float((u & 0xffffu) << 16);
}
__device__ __forceinline__ float bf2f_hi(unsigned int u) {
  return __uint_as_float(u & 0xffff0000u);
}

__device__ __forceinline__ float fast_exp2(float x) {
#if __has_builtin(__builtin_amdgcn_exp2f)
  return __builtin_amdgcn_exp2f(x);
#else
  return exp2f(x);
#endif
}

__device__ __forceinline__ float fast_rcp(float x) {
#if __has_builtin(__builtin_amdgcn_rcpf)
  return __builtin_amdgcn_rcpf(x);
#else
  return 1.0f / x;
#endif
}

__device__ __forceinline__ void async_cp16(const void* g, void* l) {
  __builtin_amdgcn_global_load_lds(
      (__attribute__((address_space(1))) void*)(g),
      (__attribute__((address_space(3))) void*)(l), 16, 0, 0);
}

// ------------- fp32 -> bf16 conversion, all 4 weights in one launch ----------
__global__ void cvt_all_kernel(const float* __restrict__ a, const float* __restrict__ b,
                               const float* __restrict__ c, const float* __restrict__ d,
                               short* __restrict__ oa, short* __restrict__ ob,
                               short* __restrict__ oc, short* __restrict__ od) {
  int i = blockIdx.x * blockDim.x + threadIdx.x;  // float4 index, 3145728 total
  const float* src; short* dst; int off;
  if (i < 786432)        { src = a; dst = oa; off = i; }
  else if (i < 1048576)  { src = b; dst = ob; off = i - 786432; }
  else if (i < 2097152)  { src = c; dst = oc; off = i - 1048576; }
  else                   { src = d; dst = od; off = i - 2097152; }
  float4 v = ((const float4*)src)[off];
  short4 o;
  o.x = f2bf(v.x); o.y = f2bf(v.y); o.z = f2bf(v.z); o.w = f2bf(v.w);
  ((short4*)dst)[off] = o;
}

// ---------------- LayerNorm (row per block) ----------------
__global__ __launch_bounds__(256) void ln_kernel(const float* __restrict__ x,
    const float* __restrict__ w, const float* __restrict__ b, short* __restrict__ out) {
  int row = blockIdx.x;
  int tid = threadIdx.x;
  float4 v = ((const float4*)(x + (size_t)row * HID))[tid];
  float s  = v.x + v.y + v.z + v.w;
  float s2 = v.x*v.x + v.y*v.y + v.z*v.z + v.w*v.w;
#pragma unroll
  for (int o = 32; o >= 1; o >>= 1) {
    s  += __shfl_xor(s,  o);
    s2 += __shfl_xor(s2, o);
  }
  __shared__ float red[8];
  int wv = tid >> 6;
  if ((tid & 63) == 0) { red[wv] = s; red[4 + wv] = s2; }
  __syncthreads();
  float ts  = red[0] + red[1] + red[2] + red[3];
  float ts2 = red[4] + red[5] + red[6] + red[7];
  float mean = ts * (1.0f / HID);
  float var  = ts2 * (1.0f / HID) - mean * mean;
  float rs = rsqrtf(var + 1e-5f);
  float4 wv4 = ((const float4*)w)[tid];
  float4 bv4 = ((const float4*)b)[tid];
  short4 o;
  o.x = f2bf((v.x - mean) * rs * wv4.x + bv4.x);
  o.y = f2bf((v.y - mean) * rs * wv4.y + bv4.y);
  o.z = f2bf((v.z - mean) * rs * wv4.z + bv4.z);
  o.w = f2bf((v.w - mean) * rs * wv4.w + bv4.w);
  ((short4*)(out + (size_t)row * HID))[tid] = o;
}

// ---- RoPE on q,k (bf16 in) -> (head, seq, 64); Q scaled by 0.125*log2(e) ----
__global__ void rope_qk_kernel(const short* __restrict__ qkvb,
    const float* __restrict__ cosb, const float* __restrict__ sinb,
    short* __restrict__ Qh, short* __restrict__ Kh) {
  int tid = blockIdx.x * blockDim.x + threadIdx.x;  // s*1024 + j*512 + h*32 + i
  int s   = tid >> 10;
  int r   = tid & 1023;
  int j   = r >> 9;
  int rem = r & 511;
  int h   = rem >> 5;
  int i   = rem & 31;
  int d   = i * 2;
  unsigned int u = *(const unsigned int*)(qkvb + (size_t)s * 3072 + j * 1024 + h * 64 + d);
  float a = bf2f_lo(u), b = bf2f_hi(u);
  float c  = cosb[s * 32 + i];
  float sn = sinb[s * 32 + i];
  float scale = (j == 0) ? 0.18033688011112043f : 1.0f;  // 0.125*log2(e)
  unsigned int o = pkbf(scale * (a * c - b * sn), scale * (a * sn + b * c));
  short* dst = (j == 0 ? Qh : Kh) + ((size_t)h * SEQ + s) * HD + d;
  *(unsigned int*)dst = o;
}

// ---------------- V transpose (bf16 in) to (head, hd, seq) ----------------
__global__ __launch_bounds__(256) void vtrans_kernel(const short* __restrict__ qkvb,
                                                     short* __restrict__ Vt) {
  __shared__ short tile[64 * 72];
  int s0   = blockIdx.x * 64;
  int head = blockIdx.y;
  int tid  = threadIdx.x;
#pragma unroll
  for (int p = 0; p < 2; p++) {
    int seg = p * 256 + tid;
    int row = seg >> 3;
    int c8  = seg & 7;
    bf16x8 v = *(const bf16x8*)(qkvb + (size_t)(s0 + row) * 3072 + 2048 + head * 64 + c8 * 8);
    *(bf16x8*)(tile + row * 72 + c8 * 8) = v;
  }
  __syncthreads();
#pragma unroll
  for (int p = 0; p < 2; p++) {
    int seg = p * 256 + tid;
    int d   = seg >> 3;
    int sc  = seg & 7;
    U8 o;
#pragma unroll
    for (int j = 0; j < 8; j++) o.s[j] = tile[(sc * 8 + j) * 72 + d];
    *(bf16x8*)(Vt + ((size_t)head * HD + d) * SEQ + s0 + sc * 8) = o.v;
  }
}

// ---------------- GEMM: C(MxN) = A(MxK) * B(NxK)^T, bf16 MFMA ----------------
// LDS XOR-swizzled; EPI 2: gelu bf16, EPI 3: bias bf16, EPI 5: split-K bf16 partial
template <int EPI>
__global__ __launch_bounds__(256) void gemm_bt_kernel(
    const short* __restrict__ A, const short* __restrict__ B,
    const float* __restrict__ bias, const float* __restrict__ resid,
    void* __restrict__ outp, int M, int N, int Klen, int Kstride) {
  __shared__ __attribute__((aligned(16))) short Alds[128 * 32];
  __shared__ __attribute__((aligned(16))) short Blds[128 * 32];
  int tid = threadIdx.x;
  int w    = tid >> 6;
  int lane = tid & 63;
  int lcol  = lane & 15;
  int lhalf = lane >> 4;
  int m0 = blockIdx.y * 128;
  int n0 = blockIdx.x * 128;
  int z  = blockIdx.z;
  int wm = (w & 1) * 64;
  int wn = (w >> 1) * 64;

  const short* apt[2];
  const short* bpt[2];
#pragma unroll
  for (int p = 0; p < 2; p++) {
    int seg = p * 256 + tid;
    int row = seg >> 2;
    int c   = (seg & 3) ^ ((row >> 1) & 3);
    apt[p] = A + (size_t)z * Klen + (size_t)(m0 + row) * Kstride + c * 8;
    bpt[p] = B + (size_t)z * Klen + (size_t)(n0 + row) * Kstride + c * 8;
  }
  int sw = (lhalf ^ ((lcol >> 1) & 3)) * 8;

  f32x4 acc[4][4];
#pragma unroll
  for (int i = 0; i < 4; i++)
#pragma unroll
    for (int j = 0; j < 4; j++) acc[i][j] = (f32x4){0.f, 0.f, 0.f, 0.f};

  for (int k0 = 0; k0 < Klen; k0 += 32) {
#pragma unroll
    for (int p = 0; p < 2; p++) {
      async_cp16(apt[p], Alds + p * 2048 + w * 512);  apt[p] += 32;
      async_cp16(bpt[p], Blds + p * 2048 + w * 512);  bpt[p] += 32;
    }
    __syncthreads();
    bf16x8 af[4], bfr[4];
#pragma unroll
    for (int i = 0; i < 4; i++)
      af[i] = *(const bf16x8*)(Alds + (wm + i * 16 + lcol) * 32 + sw);
#pragma unroll
    for (int j = 0; j < 4; j++)
      bfr[j] = *(const bf16x8*)(Blds + (wn + j * 16 + lcol) * 32 + sw);
#pragma unroll
    for (int i = 0; i < 4; i++)
#pragma unroll
      for (int j = 0; j < 4; j++)
        acc[i][j] = __builtin_amdgcn_mfma_f32_16x16x32_bf16(af[i], bfr[j], acc[i][j], 0, 0, 0);
    __syncthreads();
  }

#pragma unroll
  for (int i = 0; i < 4; i++) {
#pragma unroll
    for (int j = 0; j < 4; j++) {
#pragma unroll
      for (int r = 0; r < 4; r++) {
        int row = m0 + wm + i * 16 + lhalf * 4 + r;
        int col = n0 + wn + j * 16 + lcol;
        float v = acc[i][j][r];
        if (EPI != 5) v += bias[col];
        if (EPI == 2) {
          float t = v * (1.5957691216057308f + 0.07135481283942279f * v * v);
          float e = fast_exp2(t * -1.4426950408889634f);
          v = v * fast_rcp(1.0f + e);
          ((short*)outp)[(size_t)row * N + col] = f2bf(v);
        } else if (EPI == 3) {
          ((short*)outp)[(size_t)row * N + col] = f2bf(v);
        } else {  // EPI 5: bf16 partial
          ((short*)outp)[(size_t)z * M * N + (size_t)row * N + col] = f2bf(v);
        }
      }
    }
  }
}

// ---- Attention, 32x32x16 MFMA: wave = 32 q, block = 128 q, z-split 4 ----
// S^T = K.Q^T (C/D col=q); p=exp2 in regs; P stored [q][key] (pitch 72, bank-even);
// PV: A=V^T frag, B=P frag (ds_read_b128). Staging via registers w/ prefetch.
__global__ __launch_bounds__(256) void attn_kernel(
    const short* __restrict__ Qh, const short* __restrict__ Kh,
    const short* __restrict__ Vt, const int* __restrict__ offs,
    short* __restrict__ Opart, float* __restrict__ Lpart) {
  __shared__ __attribute__((aligned(16))) short Klds[64 * 72];
  __shared__ __attribute__((aligned(16))) short Vlds[64 * 72];
  __shared__ __attribute__((aligned(16))) short Plds[4][32 * 72];
  int head = blockIdx.y;
  int q0   = blockIdx.x * 128;
  int z    = blockIdx.z;
  int tid  = threadIdx.x;
  int w    = tid >> 6;
  int lane = tid & 63;
  int l31  = lane & 31;
  int lh   = lane >> 5;
  int o1 = offs[1], o2 = offs[2], o3 = offs[3];

  int qrow = q0 + w * 32 + l31;
  const short* qb = Qh + ((size_t)head * SEQ + qrow) * HD + lh * 8;
  bf16x8 qf0 = *(const bf16x8*)(qb);
  bf16x8 qf1 = *(const bf16x8*)(qb + 16);
  bf16x8 qf2 = *(const bf16x8*)(qb + 32);
  bf16x8 qf3 = *(const bf16x8*)(qb + 48);
  int sq = (qrow >= o1) + (qrow >= o2) + (qrow >= o3);
  U8 qe;
  qe.u[0] = 0; qe.u[1] = 0; qe.u[2] = 0; qe.u[3] = 0;
  if (lh == 0) qe.s[sq] = (short)0x3FB9;  // bf16(log2e)

  // staging: thread -> (row = tid>>3, chunk = tid&7), two row-groups of 32
  int srow = tid >> 3;
  int sc   = tid & 7;
  int tbeg = z * 512;
  const short* kg0 = Kh + ((size_t)head * SEQ + tbeg + srow) * HD + sc * 8;
  const short* kg1 = kg0 + (size_t)32 * HD;
  const short* vg0 = Vt + ((size_t)head * HD + srow) * SEQ + tbeg + sc * 8;
  const short* vg1 = vg0 + (size_t)32 * SEQ;
  short* kw0 = Klds + srow * 72 + sc * 8;
  short* kw1 = kw0 + 32 * 72;
  short* vw0 = Vlds + srow * 72 + sc * 8;
  short* vw1 = vw0 + 32 * 72;

  bf16x8 rk0 = *(const bf16x8*)kg0;  kg0 += (size_t)64 * HD;
  bf16x8 rk1 = *(const bf16x8*)kg1;  kg1 += (size_t)64 * HD;
  bf16x8 rv0 = *(const bf16x8*)vg0;  vg0 += 64;
  bf16x8 rv1 = *(const bf16x8*)vg1;  vg1 += 64;

  f32x16 oA, oB;
#pragma unroll
  for (int i = 0; i < 16; i++) { oA[i] = 0.f; oB[i] = 0.f; }
  float l_lane = 0.f;

  short* prow = Plds[w] + l31 * 72;                    // P row for this lane's q
  const short* ka_base = Klds + l31 * 72 + lh * 8;     // + kt*32*72 + c*16
  const short* va_base = Vlds + l31 * 72 + lh * 8;     // + dt*32*72 + kc*16
  const short* pb_base = prow + lh * 8;                // + kc*16

  for (int t0 = 0; t0 < 512; t0 += 64) {
    __syncthreads();
    *(bf16x8*)kw0 = rk0;
    *(bf16x8*)kw1 = rk1;
    *(bf16x8*)vw0 = rv0;
    *(bf16x8*)vw1 = rv1;
    if (t0 + 64 < 512) {  // prefetch next tile (overlaps compute below)
      rk0 = *(const bf16x8*)kg0;  kg0 += (size_t)64 * HD;
      rk1 = *(const bf16x8*)kg1;  kg1 += (size_t)64 * HD;
      rv0 = *(const bf16x8*)vg0;  vg0 += 64;
      rv1 = *(const bf16x8*)vg1;  vg1 += 64;
    }
    __syncthreads();

#pragma unroll
    for (int kt = 0; kt < 2; kt++) {
      int key = tbeg + t0 + kt * 32 + l31;
      int sk = (key >= o1) + (key >= o2) + (key >= o3);
      U8 ke;
      ke.u[0] = 0; ke.u[1] = 0; ke.u[2] = 0; ke.u[3] = 0;
      if (lh == 0) ke.s[sk] = (short)0x3F80;

      const short* ka = ka_base + kt * (32 * 72);
      f32x16 s;
#pragma unroll
      for (int i = 0; i < 16; i++) s[i] = 0.f;
      s = __builtin_amdgcn_mfma_f32_32x32x16_bf16(*(const bf16x8*)(ka),      qf0, s, 0, 0, 0);
      s = __builtin_amdgcn_mfma_f32_32x32x16_bf16(*(const bf16x8*)(ka + 16), qf1, s, 0, 0, 0);
      s = __builtin_amdgcn_mfma_f32_32x32x16_bf16(*(const bf16x8*)(ka + 32), qf2, s, 0, 0, 0);
      s = __builtin_amdgcn_mfma_f32_32x32x16_bf16(*(const bf16x8*)(ka + 48), qf3, s, 0, 0, 0);
      s = __builtin_amdgcn_mfma_f32_32x32x16_bf16(ke.v, qe.v, s, 0, 0, 0);

      float e[16];
#pragma unroll
      for (int i = 0; i < 16; i++) e[i] = fast_exp2(s[i]);
#pragma unroll
      for (int i = 0; i < 16; i++) l_lane += e[i];
#pragma unroll
      for (int g = 0; g < 4; g++) {
        uint2 pw;  // D rows for reg group g: key = kt*32 + g*8 + lh*4 + (0..3)
        pw.x = __builtin_amdgcn_perm(__float_as_uint(e[4 * g + 1]),
                                     __float_as_uint(e[4 * g + 0]), 0x07060302);
        pw.y = __builtin_amdgcn_perm(__float_as_uint(e[4 * g + 3]),
                                     __float_as_uint(e[4 * g + 2]), 0x07060302);
        *(uint2*)(prow + kt * 32 + g * 8 + lh * 4) = pw;
      }
    }

#pragma unroll
    for (int kc = 0; kc < 4; kc++) {
      bf16x8 pf = *(const bf16x8*)(pb_base + kc * 16);
      bf16x8 va = *(const bf16x8*)(va_base + kc * 16);
      bf16x8 vb = *(const bf16x8*)(va_base + 32 * 72 + kc * 16);
      oA = __builtin_amdgcn_mfma_f32_32x32x16_bf16(va, pf, oA, 0, 0, 0);
      oB = __builtin_amdgcn_mfma_f32_32x32x16_bf16(vb, pf, oB, 0, 0, 0);
    }
  }

  float lsum = l_lane + __shfl_xor(l_lane, 32);
  // O store: col=q (l31), d = dt*32 + g*8 + lh*4 + (0..3)
  short* op = Opart + ((size_t)z * SEQ + qrow) * HID + head * HD + lh * 4;
#pragma unroll
  for (int g = 0; g < 4; g++) {
    uint2 ua, ub;
    ua.x = pkbf(oA[4 * g + 0], oA[4 * g + 1]);
    ua.y = pkbf(oA[4 * g + 2], oA[4 * g + 3]);
    ub.x = pkbf(oB[4 * g + 0], oB[4 * g + 1]);
    ub.y = pkbf(oB[4 * g + 2], oB[4 * g + 3]);
    *(uint2*)(op + g * 8) = ua;
    *(uint2*)(op + 32 + g * 8) = ub;
  }
  if (lh == 0)
    Lpart[((size_t)z * NH + head) * SEQ + qrow] = lsum;
}

// ---- merge 4 bf16 z-partials, normalize by sum(l), out bf16 ----
__global__ __launch_bounds__(256) void attn_merge_kernel(
    const short* __restrict__ Opart, const float* __restrict__ Lpart,
    short* __restrict__ attn) {
  int i = blockIdx.x * blockDim.x + threadIdx.x;  // uint2 (4 bf16) index
  int col4 = i & 255;
  int row  = i >> 8;
  int head = col4 >> 4;
  float acc0 = 0.f, acc1 = 0.f, acc2 = 0.f, acc3 = 0.f, l = 0.f;
#pragma unroll
  for (int zz = 0; zz < 4; zz++) {
    uint2 p = ((const uint2*)(Opart + (size_t)zz * SEQ * HID))[i];
    acc0 += bf2f_lo(p.x); acc1 += bf2f_hi(p.x);
    acc2 += bf2f_lo(p.y); acc3 += bf2f_hi(p.y);
    l += Lpart[((size_t)zz * NH + head) * SEQ + row];
  }
  float rl = fast_rcp(l);
  uint2 o;
  o.x = pkbf(acc0 * rl, acc1 * rl);
  o.y = pkbf(acc2 * rl, acc3 * rl);
  ((uint2*)attn)[i] = o;
}

// ------- split-K bf16-partial merge + bias + residual + LayerNorm -------
__global__ __launch_bounds__(256) void merge_ln_kernel(
    const short* __restrict__ part, const float* __restrict__ bias,
    const float* __restrict__ resid, const float* __restrict__ w,
    const float* __restrict__ b, float* __restrict__ x1, short* __restrict__ h1) {
  int row = blockIdx.x;
  int tid = threadIdx.x;
  size_t idx = (size_t)row * HID / 4 + tid;
  float4 v = {0.f, 0.f, 0.f, 0.f};
#pragma unroll
  for (int z = 0; z < 4; z++) {
    uint2 p = ((const uint2*)(part + (size_t)z * SEQ * HID))[idx];
    v.x += bf2f_lo(p.x); v.y += bf2f_hi(p.x);
    v.z += bf2f_lo(p.y); v.w += bf2f_hi(p.y);
  }
  float4 bi = ((const float4*)bias)[tid];
  float4 rs4 = ((const float4*)(resid + (size_t)row * HID))[tid];
  v.x += bi.x + rs4.x; v.y += bi.y + rs4.y; v.z += bi.z + rs4.z; v.w += bi.w + rs4.w;
  ((float4*)(x1 + (size_t)row * HID))[tid] = v;
  float s  = v.x + v.y + v.z + v.w;
  float s2 = v.x*v.x + v.y*v.y + v.z*v.z + v.w*v.w;
#pragma unroll
  for (int o = 32; o >= 1; o >>= 1) {
    s  += __shfl_xor(s,  o);
    s2 += __shfl_xor(s2, o);
  }
  __shared__ float red[8];
  int wv = tid >> 6;
  if ((tid & 63) == 0) { red[wv] = s; red[4 + wv] = s2; }
  __syncthreads();
  float ts  = red[0] + red[1] + red[2] + red[3];
  float ts2 = red[4] + red[5] + red[6] + red[7];
  float mean = ts * (1.0f / HID);
  float var  = ts2 * (1.0f / HID) - mean * mean;
  float rsq = rsqrtf(var + 1e-5f);
  float4 wv4 = ((const float4*)w)[tid];
  float4 bv4 = ((const float4*)b)[tid];
  short4 o;
  o.x = f2bf((v.x - mean) * rsq * wv4.x + bv4.x);
  o.y = f2bf((v.y - mean) * rsq * wv4.y + bv4.y);
  o.z = f2bf((v.z - mean) * rsq * wv4.z + bv4.z);
  o.w = f2bf((v.w - mean) * rsq * wv4.w + bv4.w);
  ((short4*)(h1 + (size_t)row * HID))[tid] = o;
}

// ------- split-K bf16-partial merge + bias + residual -> fp32 out -------
__global__ __launch_bounds__(256) void merge_bias_kernel(
    const short* __restrict__ part, const float* __restrict__ bias,
    const float* __restrict__ resid, float* __restrict__ out) {
  int i = blockIdx.x * blockDim.x + threadIdx.x;
  int col4 = i & 255;
  float4 v = {0.f, 0.f, 0.f, 0.f};
#pragma unroll
  for (int z = 0; z < 4; z++) {
    uint2 p = ((const uint2*)(part + (size_t)z * SEQ * HID))[i];
    v.x += bf2f_lo(p.x); v.y += bf2f_hi(p.x);
    v.z += bf2f_lo(p.y); v.w += bf2f_hi(p.y);
  }
  float4 bi = ((const float4*)bias)[col4];
  float4 rs = ((const float4*)resid)[i];
  float4 o;
  o.x = v.x + bi.x + rs.x;
  o.y = v.y + bi.y + rs.y;
  o.z = v.z + bi.z + rs.z;
  o.w = v.w + bi.w + rs.w;
  ((float4*)out)[i] = o;
}

extern "C" void kernel_launch(void* const* d_in, const int* in_sizes, int n_in,
                              void* d_out, int out_size, void* d_ws, size_t ws_size,
                              hipStream_t stream) {
  const float* x      = (const float*)d_in[0];
  const float* ropec  = (const float*)d_in[1];
  const float* ropes  = (const float*)d_in[2];
  const float* n0w    = (const float*)d_in[3];
  const float* n0b    = (const float*)d_in[4];
  const float* n1w    = (const float*)d_in[5];
  const float* n1b    = (const float*)d_in[6];
  const float* wqkv_w = (const float*)d_in[7];
  const float* wqkv_b = (const float*)d_in[8];
  const float* wo_w   = (const float*)d_in[9];
  const float* wo_b   = (const float*)d_in[10];
  const float* up_w   = (const float*)d_in[11];
  const float* up_b   = (const float*)d_in[12];
  const float* down_w = (const float*)d_in[13];
  const float* down_b = (const float*)d_in[14];
  const int*   offs   = (const int*)d_in[15];
  float* out = (float*)d_out;

  char* base = (char*)d_ws;
  // ---- static layout, lifetime-aliased (peak ~88.6 MB) ----
  short* wqkv_bf = (short*)(base + 0);            //  6.3 MB, whole run
  short* wo_bf   = (short*)(base + 6291456);      //  2.1 MB, whole run
  short* up_bf   = (short*)(base + 8388608);      //  8.4 MB, whole run
  short* down_bf = (short*)(base + 16777216);     //  8.4 MB, whole run
  short* h0      = (short*)(base + 25165824);     //  4.2 MB, dead after qkv gemm
  short* qkv_bf  = (short*)(base + 29360128);     // 12.6 MB, dead after rope/vtrans
  short* Qh      = (short*)(base + 41943040);     //  4.2 MB, dead after attn
  short* Kh      = (short*)(base + 46137344);     //  4.2 MB, dead after attn
  short* Vt      = (short*)(base + 50331648);     //  4.2 MB, dead after attn
  short* Opart   = (short*)(base + 54525952);     // 16.8 MB, dead after attn_merge
  float* Lpart   = (float*)(base + 71303168);     //  0.5 MB
  short* attn    = (short*)(base + 71827456);     //  4.2 MB, dead after wo gemm
  float* x1      = (float*)(base + 76021760);     //  8.4 MB, live to end
  short* h1      = (short*)(base + 84410368);     //  4.2 MB, dead after up gemm
  short* wopart  = (short*)(base + 25165824);     // 16.8 MB -> 41.9 MB (h0..Vt dead)
  short* u       = (short*)(base + 25165824);     // 16.8 MB -> 41.9 MB
  short* dnpart  = (short*)(base + 41943040);     // 16.8 MB -> 58.7 MB (Qh..Opart dead)

  cvt_all_kernel<<<12288, 256, 0, stream>>>(wqkv_w, wo_w, up_w, down_w,
                                            wqkv_bf, wo_bf, up_bf, down_bf);
  ln_kernel<<<2048, 256, 0, stream>>>(x, n0w, n0b, h0);
  gemm_bt_kernel<3><<<dim3(24, 16), 256, 0, stream>>>(h0, wqkv_bf, wqkv_b, nullptr,
                                                      qkv_bf, 2048, 3072, 1024, 1024);
  rope_qk_kernel<<<8192, 256, 0, stream>>>(qkv_bf, ropec, ropes, Qh, Kh);
  vtrans_kernel<<<dim3(32, 16), 256, 0, stream>>>(qkv_bf, Vt);
  attn_kernel<<<dim3(16, 16, 4), 256, 0, stream>>>(Qh, Kh, Vt, offs, Opart, Lpart);
  attn_merge_kernel<<<2048, 256, 0, stream>>>(Opart, Lpart, attn);
  gemm_bt_kernel<5><<<dim3(8, 16, 4), 256, 0, stream>>>(attn, wo_bf, nullptr, nullptr,
                                                        wopart, 2048, 1024, 256, 1024);
  merge_ln_kernel<<<2048, 256, 0, stream>>>(wopart, wo_b, x, n1w, n1b, x1, h1);
  gemm_bt_kernel<2><<<dim3(32, 16), 256, 0, stream>>>(h1, up_bf, up_b, nullptr,
                                                      u, 2048, 4096, 1024, 1024);
  gemm_bt_kernel<5><<<dim3(8, 16, 4), 256, 0, stream>>>(u, down_bf, nullptr, nullptr,
                                                        dnpart, 2048, 1024, 1024, 4096);
  merge_bias_kernel<<<2048, 256, 0, stream>>>(dnpart, down_b, x1, out);
}

// Round 12
// 287.941 us; speedup vs baseline: 1.1447x; 1.1447x over previous
//
#include <hip/hip_runtime.h>
#include <hip/hip_bf16.h>
#include <math.h>

#define SEQ 2048
#define HID 1024
#define NH 16
#define HD 64

using f32x4  = __attribute__((ext_vector_type(4))) float;
using bf16x8 = __attribute__((ext_vector_type(8))) short;

union U8 { unsigned int u[4]; bf16x8 v; short s[8]; };

__device__ __forceinline__ short f2bf(float f) {
  unsigned int x = __float_as_uint(f);
  unsigned int r = (x + 0x7fffu + ((x >> 16) & 1u)) >> 16;
  return (short)(r & 0xffffu);
}

__device__ __forceinline__ unsigned int pkbf(float a, float b) {
  return ((unsigned int)(unsigned short)f2bf(a)) |
         (((unsigned int)(unsigned short)f2bf(b)) << 16);
}

__device__ __forceinline__ float bf2f_lo(unsigned int u) {
  return __uint_as_float((u & 0xffffu) << 16);
}
__device__ __forceinline__ float bf2f_hi(unsigned int u) {
  return __uint_as_float(u & 0xffff0000u);
}

__device__ __forceinline__ float fast_exp2(float x) {
#if __has_builtin(__builtin_amdgcn_exp2f)
  return __builtin_amdgcn_exp2f(x);
#else
  return exp2f(x);
#endif
}

__device__ __forceinline__ float fast_rcp(float x) {
#if __has_builtin(__builtin_amdgcn_rcpf)
  return __builtin_amdgcn_rcpf(x);
#else
  return 1.0f / x;
#endif
}

__device__ __forceinline__ void async_cp16(const void* g, void* l) {
  __builtin_amdgcn_global_load_lds(
      (__attribute__((address_space(1))) void*)(g),
      (__attribute__((address_space(3))) void*)(l), 16, 0, 0);
}

// ------------- fp32 -> bf16 conversion, all 4 weights in one launch ----------
__global__ void cvt_all_kernel(const float* __restrict__ a, const float* __restrict__ b,
                               const float* __restrict__ c, const float* __restrict__ d,
                               short* __restrict__ oa, short* __restrict__ ob,
                               short* __restrict__ oc, short* __restrict__ od) {
  int i = blockIdx.x * blockDim.x + threadIdx.x;  // float4 index, 3145728 total
  const float* src; short* dst; int off;
  if (i < 786432)        { src = a; dst = oa; off = i; }
  else if (i < 1048576)  { src = b; dst = ob; off = i - 786432; }
  else if (i < 2097152)  { src = c; dst = oc; off = i - 1048576; }
  else                   { src = d; dst = od; off = i - 2097152; }
  float4 v = ((const float4*)src)[off];
  short4 o;
  o.x = f2bf(v.x); o.y = f2bf(v.y); o.z = f2bf(v.z); o.w = f2bf(v.w);
  ((short4*)dst)[off] = o;
}

// ---------------- LayerNorm (row per block) ----------------
__global__ __launch_bounds__(256) void ln_kernel(const float* __restrict__ x,
    const float* __restrict__ w, const float* __restrict__ b, short* __restrict__ out) {
  int row = blockIdx.x;
  int tid = threadIdx.x;
  float4 v = ((const float4*)(x + (size_t)row * HID))[tid];
  float s  = v.x + v.y + v.z + v.w;
  float s2 = v.x*v.x + v.y*v.y + v.z*v.z + v.w*v.w;
#pragma unroll
  for (int o = 32; o >= 1; o >>= 1) {
    s  += __shfl_xor(s,  o);
    s2 += __shfl_xor(s2, o);
  }
  __shared__ float red[8];
  int wv = tid >> 6;
  if ((tid & 63) == 0) { red[wv] = s; red[4 + wv] = s2; }
  __syncthreads();
  float ts  = red[0] + red[1] + red[2] + red[3];
  float ts2 = red[4] + red[5] + red[6] + red[7];
  float mean = ts * (1.0f / HID);
  float var  = ts2 * (1.0f / HID) - mean * mean;
  float rs = rsqrtf(var + 1e-5f);
  float4 wv4 = ((const float4*)w)[tid];
  float4 bv4 = ((const float4*)b)[tid];
  short4 o;
  o.x = f2bf((v.x - mean) * rs * wv4.x + bv4.x);
  o.y = f2bf((v.y - mean) * rs * wv4.y + bv4.y);
  o.z = f2bf((v.z - mean) * rs * wv4.z + bv4.z);
  o.w = f2bf((v.w - mean) * rs * wv4.w + bv4.w);
  ((short4*)(out + (size_t)row * HID))[tid] = o;
}

// ---- Fused RoPE(q,k) + V-transpose, per (s0-block of 64, head) ----
// Q scaled by 0.125*log2(e); outputs Qh/Kh (head, seq, 64) and Vt (head, hd, seq).
__global__ __launch_bounds__(256) void ropev_kernel(const short* __restrict__ qkvb,
    const float* __restrict__ cosb, const float* __restrict__ sinb,
    short* __restrict__ Qh, short* __restrict__ Kh, short* __restrict__ Vt) {
  __shared__ short tile[64 * 72];
  int s0   = blockIdx.x * 64;
  int head = blockIdx.y;
  int tid  = threadIdx.x;
  // ---- V: stage 64x64 tile, transposed write ----
#pragma unroll
  for (int p = 0; p < 2; p++) {
    int seg = p * 256 + tid;
    int row = seg >> 3;
    int c8  = seg & 7;
    bf16x8 v = *(const bf16x8*)(qkvb + (size_t)(s0 + row) * 3072 + 2048 + head * 64 + c8 * 8);
    *(bf16x8*)(tile + row * 72 + c8 * 8) = v;
  }
  // ---- RoPE on q and k while V tile settles ----
  int sl = tid >> 3;          // 0..31 local s
  int c  = tid & 7;           // pair-quad index: pairs c*4 .. c*4+3
#pragma unroll
  for (int j = 0; j < 2; j++) {        // 0 = q, 1 = k
    float scale = (j == 0) ? 0.18033688011112043f : 1.0f;  // 0.125*log2(e)
    short* dstm = (j == 0) ? Qh : Kh;
#pragma unroll
    for (int half = 0; half < 2; half++) {
      int s = s0 + half * 32 + sl;
      uint4 uu = *(const uint4*)(qkvb + (size_t)s * 3072 + j * 1024 + head * 64 + c * 8);
      float4 cs = *(const float4*)(cosb + s * 32 + c * 4);
      float4 sn = *(const float4*)(sinb + s * 32 + c * 4);
      uint4 oo;
      {
        float a = bf2f_lo(uu.x), b = bf2f_hi(uu.x);
        oo.x = pkbf(scale * (a * cs.x - b * sn.x), scale * (a * sn.x + b * cs.x));
        a = bf2f_lo(uu.y); b = bf2f_hi(uu.y);
        oo.y = pkbf(scale * (a * cs.y - b * sn.y), scale * (a * sn.y + b * cs.y));
        a = bf2f_lo(uu.z); b = bf2f_hi(uu.z);
        oo.z = pkbf(scale * (a * cs.z - b * sn.z), scale * (a * sn.z + b * cs.z));
        a = bf2f_lo(uu.w); b = bf2f_hi(uu.w);
        oo.w = pkbf(scale * (a * cs.w - b * sn.w), scale * (a * sn.w + b * cs.w));
      }
      *(uint4*)(dstm + ((size_t)head * SEQ + s) * HD + c * 8) = oo;
    }
  }
  __syncthreads();
#pragma unroll
  for (int p = 0; p < 2; p++) {
    int seg = p * 256 + tid;
    int d   = seg >> 3;
    int sc  = seg & 7;
    U8 o;
#pragma unroll
    for (int jj = 0; jj < 8; jj++) o.s[jj] = tile[(sc * 8 + jj) * 72 + d];
    *(bf16x8*)(Vt + ((size_t)head * HD + d) * SEQ + s0 + sc * 8) = o.v;
  }
}

// ---------------- GEMM: C(MxN) = A(MxK) * B(NxK)^T, bf16 MFMA ----------------
// LDS XOR-swizzled; EPI 2: gelu bf16, EPI 3: bias bf16, EPI 5: split-K bf16 partial
template <int EPI>
__global__ __launch_bounds__(256) void gemm_bt_kernel(
    const short* __restrict__ A, const short* __restrict__ B,
    const float* __restrict__ bias, const float* __restrict__ resid,
    void* __restrict__ outp, int M, int N, int Klen, int Kstride) {
  __shared__ __attribute__((aligned(16))) short Alds[128 * 32];
  __shared__ __attribute__((aligned(16))) short Blds[128 * 32];
  int tid = threadIdx.x;
  int w    = tid >> 6;
  int lane = tid & 63;
  int lcol  = lane & 15;
  int lhalf = lane >> 4;
  int m0 = blockIdx.y * 128;
  int n0 = blockIdx.x * 128;
  int z  = blockIdx.z;
  int wm = (w & 1) * 64;
  int wn = (w >> 1) * 64;

  const short* apt[2];
  const short* bpt[2];
#pragma unroll
  for (int p = 0; p < 2; p++) {
    int seg = p * 256 + tid;
    int row = seg >> 2;
    int c   = (seg & 3) ^ ((row >> 1) & 3);
    apt[p] = A + (size_t)z * Klen + (size_t)(m0 + row) * Kstride + c * 8;
    bpt[p] = B + (size_t)z * Klen + (size_t)(n0 + row) * Kstride + c * 8;
  }
  int sw = (lhalf ^ ((lcol >> 1) & 3)) * 8;

  f32x4 acc[4][4];
#pragma unroll
  for (int i = 0; i < 4; i++)
#pragma unroll
    for (int j = 0; j < 4; j++) acc[i][j] = (f32x4){0.f, 0.f, 0.f, 0.f};

  for (int k0 = 0; k0 < Klen; k0 += 32) {
#pragma unroll
    for (int p = 0; p < 2; p++) {
      async_cp16(apt[p], Alds + p * 2048 + w * 512);  apt[p] += 32;
      async_cp16(bpt[p], Blds + p * 2048 + w * 512);  bpt[p] += 32;
    }
    __syncthreads();
    bf16x8 af[4], bfr[4];
#pragma unroll
    for (int i = 0; i < 4; i++)
      af[i] = *(const bf16x8*)(Alds + (wm + i * 16 + lcol) * 32 + sw);
#pragma unroll
    for (int j = 0; j < 4; j++)
      bfr[j] = *(const bf16x8*)(Blds + (wn + j * 16 + lcol) * 32 + sw);
#pragma unroll
    for (int i = 0; i < 4; i++)
#pragma unroll
      for (int j = 0; j < 4; j++)
        acc[i][j] = __builtin_amdgcn_mfma_f32_16x16x32_bf16(af[i], bfr[j], acc[i][j], 0, 0, 0);
    __syncthreads();
  }

#pragma unroll
  for (int i = 0; i < 4; i++) {
#pragma unroll
    for (int j = 0; j < 4; j++) {
#pragma unroll
      for (int r = 0; r < 4; r++) {
        int row = m0 + wm + i * 16 + lhalf * 4 + r;
        int col = n0 + wn + j * 16 + lcol;
        float v = acc[i][j][r];
        if (EPI != 5) v += bias[col];
        if (EPI == 2) {
          float t = v * (1.5957691216057308f + 0.07135481283942279f * v * v);
          float e = fast_exp2(t * -1.4426950408889634f);
          v = v * fast_rcp(1.0f + e);
          ((short*)outp)[(size_t)row * N + col] = f2bf(v);
        } else if (EPI == 3) {
          ((short*)outp)[(size_t)row * N + col] = f2bf(v);
        } else {  // EPI 5: bf16 partial
          ((short*)outp)[(size_t)z * M * N + (size_t)row * N + col] = f2bf(v);
        }
      }
    }
  }
}

// ---- Attention (R8-proven): 64 q/block, single per-wave Plds, z-split 4 ----
__global__ __launch_bounds__(256) void attn_kernel(
    const short* __restrict__ Qh, const short* __restrict__ Kh,
    const short* __restrict__ Vt, const int* __restrict__ offs,
    short* __restrict__ Opart, float* __restrict__ Lpart) {
  __shared__ __attribute__((aligned(16))) short Klds[64 * 64];
  __shared__ __attribute__((aligned(16))) short Vlds[64 * 64];
  __shared__ __attribute__((aligned(16))) unsigned int Plds[4][16 * 34];
  int head = blockIdx.y;
  int q0   = blockIdx.x * 64;
  int z    = blockIdx.z;
  int tid  = threadIdx.x;
  int w    = tid >> 6;
  int lane = tid & 63;
  int lcol = lane & 15;
  int h    = lane >> 4;
  int s7   = lcol & 7;
  int o1 = offs[1], o2 = offs[2], o3 = offs[3];

  int qrow = q0 + w * 16 + lcol;
  const short* qb = Qh + ((size_t)head * SEQ + qrow) * HD;
  bf16x8 qf0 = *(const bf16x8*)(qb + h * 8);
  bf16x8 qf1 = *(const bf16x8*)(qb + 32 + h * 8);
  int sq = (qrow >= o1) + (qrow >= o2) + (qrow >= o3);
  U8 qe;
  qe.u[0] = 0; qe.u[1] = 0; qe.u[2] = 0; qe.u[3] = 0;
  if (h == 0) qe.s[sq] = (short)0x3FB9;  // bf16(log2e)

  bf16x8 ones;
#pragma unroll
  for (int i = 0; i < 8; i++) ones[i] = 0x3F80;

  int kb0 = lcol * 64 + ((h ^ s7) * 8);
  int kb1 = lcol * 64 + (((4 + h) ^ s7) * 8);
  int vb0 = kb0, vb1 = kb1;
  int pwb = lcol * 34 + h * 2;
  int prb = lcol * 34 + h * 4;

  int tbeg = z * 512;
  const short* kp0; const short* kp1; const short* vp0; const short* vp1;
  {
    int seg = tid, row = seg >> 3, g = (seg & 7) ^ (row & 7);
    kp0 = Kh + ((size_t)head * SEQ + tbeg + row) * HD + g * 8;
    vp0 = Vt + ((size_t)head * HD + row) * SEQ + tbeg + g * 8;
    seg = 256 + tid; row = seg >> 3; g = (seg & 7) ^ (row & 7);
    kp1 = Kh + ((size_t)head * SEQ + tbeg + row) * HD + g * 8;
    vp1 = Vt + ((size_t)head * HD + row) * SEQ + tbeg + g * 8;
  }

  f32x4 o_acc[4];
#pragma unroll
  for (int nt = 0; nt < 4; nt++) o_acc[nt] = (f32x4){0.f, 0.f, 0.f, 0.f};
  f32x4 acc_l = (f32x4){0.f, 0.f, 0.f, 0.f};

  for (int t0 = 0; t0 < 512; t0 += 64) {
    async_cp16(kp0, Klds + w * 512);          kp0 += 64 * HD;
    async_cp16(kp1, Klds + 2048 + w * 512);   kp1 += 64 * HD;
    async_cp16(vp0, Vlds + w * 512);          vp0 += 64;
    async_cp16(vp1, Vlds + 2048 + w * 512);   vp1 += 64;
    __syncthreads();

#pragma unroll
    for (int n = 0; n < 4; n++) {
      bf16x8 kf0 = *(const bf16x8*)(Klds + n * 1024 + kb0);
      bf16x8 kf1 = *(const bf16x8*)(Klds + n * 1024 + kb1);
      int key = tbeg + t0 + n * 16 + lcol;
      int sk = (key >= o1) + (key >= o2) + (key >= o3);
      U8 ke;
      ke.u[0] = (h == 0) ? ((sk == 0) ? 0x00003F80u : (sk == 1) ? 0x3F800000u : 0u) : 0u;
      ke.u[1] = (h == 0) ? ((sk == 2) ? 0x00003F80u : (sk == 3) ? 0x3F800000u : 0u) : 0u;
      ke.u[2] = 0; ke.u[3] = 0;

      f32x4 sacc = (f32x4){0.f, 0.f, 0.f, 0.f};
      sacc = __builtin_amdgcn_mfma_f32_16x16x32_bf16(kf0, qf0, sacc, 0, 0, 0);
      sacc = __builtin_amdgcn_mfma_f32_16x16x32_bf16(kf1, qf1, sacc, 0, 0, 0);
      sacc = __builtin_amdgcn_mfma_f32_16x16x32_bf16(ke.v, qe.v, sacc, 0, 0, 0);

      float p0 = fast_exp2(sacc[0]);
      float p1 = fast_exp2(sacc[1]);
      float p2 = fast_exp2(sacc[2]);
      float p3 = fast_exp2(sacc[3]);
      uint2 pw;
      pw.x = __builtin_amdgcn_perm(__float_as_uint(p1), __float_as_uint(p0), 0x07060302);
      pw.y = __builtin_amdgcn_perm(__float_as_uint(p3), __float_as_uint(p2), 0x07060302);
      *(uint2*)&Plds[w][pwb + n * 8] = pw;
    }

#pragma unroll
    for (int kc = 0; kc < 2; kc++) {
      uint2 a = *(const uint2*)&Plds[w][prb + kc * 16];
      uint2 b = *(const uint2*)&Plds[w][prb + kc * 16 + 2];
      U8 pu;
      pu.u[0] = a.x; pu.u[1] = a.y; pu.u[2] = b.x; pu.u[3] = b.y;
      int vb = kc ? vb1 : vb0;
#pragma unroll
      for (int nt = 0; nt < 4; nt++) {
        bf16x8 vf = *(const bf16x8*)(Vlds + nt * 1024 + vb);
        o_acc[nt] = __builtin_amdgcn_mfma_f32_16x16x32_bf16(vf, pu.v, o_acc[nt], 0, 0, 0);
      }
      acc_l = __builtin_amdgcn_mfma_f32_16x16x32_bf16(ones, pu.v, acc_l, 0, 0, 0);
    }
    __syncthreads();
  }

  short* op = Opart + ((size_t)z * SEQ + qrow) * HID + head * HD + h * 4;
#pragma unroll
  for (int nt = 0; nt < 4; nt++) {
    uint2 ua;
    ua.x = pkbf(o_acc[nt][0], o_acc[nt][1]);
    ua.y = pkbf(o_acc[nt][2], o_acc[nt][3]);
    *(uint2*)(op + nt * 16) = ua;
  }
  if (lane < 16)
    Lpart[((size_t)z * NH + head) * SEQ + qrow] = acc_l[0];
}

// ---- merge 4 bf16 z-partials, normalize by sum(l), out bf16 ----
__global__ __launch_bounds__(256) void attn_merge_kernel(
    const short* __restrict__ Opart, const float* __restrict__ Lpart,
    short* __restrict__ attn) {
  int i = blockIdx.x * blockDim.x + threadIdx.x;  // uint2 (4 bf16) index
  int col4 = i & 255;
  int row  = i >> 8;
  int head = col4 >> 4;
  float acc0 = 0.f, acc1 = 0.f, acc2 = 0.f, acc3 = 0.f, l = 0.f;
#pragma unroll
  for (int zz = 0; zz < 4; zz++) {
    uint2 p = ((const uint2*)(Opart + (size_t)zz * SEQ * HID))[i];
    acc0 += bf2f_lo(p.x); acc1 += bf2f_hi(p.x);
    acc2 += bf2f_lo(p.y); acc3 += bf2f_hi(p.y);
    l += Lpart[((size_t)zz * NH + head) * SEQ + row];
  }
  float rl = fast_rcp(l);
  uint2 o;
  o.x = pkbf(acc0 * rl, acc1 * rl);
  o.y = pkbf(acc2 * rl, acc3 * rl);
  ((uint2*)attn)[i] = o;
}

// ------- split-K bf16-partial merge + bias + residual + LayerNorm -------
__global__ __launch_bounds__(256) void merge_ln_kernel(
    const short* __restrict__ part, const float* __restrict__ bias,
    const float* __restrict__ resid, const float* __restrict__ w,
    const float* __restrict__ b, float* __restrict__ x1, short* __restrict__ h1) {
  int row = blockIdx.x;
  int tid = threadIdx.x;
  size_t idx = (size_t)row * HID / 4 + tid;
  float4 v = {0.f, 0.f, 0.f, 0.f};
#pragma unroll
  for (int z = 0; z < 4; z++) {
    uint2 p = ((const uint2*)(part + (size_t)z * SEQ * HID))[idx];
    v.x += bf2f_lo(p.x); v.y += bf2f_hi(p.x);
    v.z += bf2f_lo(p.y); v.w += bf2f_hi(p.y);
  }
  float4 bi = ((const float4*)bias)[tid];
  float4 rs4 = ((const float4*)(resid + (size_t)row * HID))[tid];
  v.x += bi.x + rs4.x; v.y += bi.y + rs4.y; v.z += bi.z + rs4.z; v.w += bi.w + rs4.w;
  ((float4*)(x1 + (size_t)row * HID))[tid] = v;
  float s  = v.x + v.y + v.z + v.w;
  float s2 = v.x*v.x + v.y*v.y + v.z*v.z + v.w*v.w;
#pragma unroll
  for (int o = 32; o >= 1; o >>= 1) {
    s  += __shfl_xor(s,  o);
    s2 += __shfl_xor(s2, o);
  }
  __shared__ float red[8];
  int wv = tid >> 6;
  if ((tid & 63) == 0) { red[wv] = s; red[4 + wv] = s2; }
  __syncthreads();
  float ts  = red[0] + red[1] + red[2] + red[3];
  float ts2 = red[4] + red[5] + red[6] + red[7];
  float mean = ts * (1.0f / HID);
  float var  = ts2 * (1.0f / HID) - mean * mean;
  float rsq = rsqrtf(var + 1e-5f);
  float4 wv4 = ((const float4*)w)[tid];
  float4 bv4 = ((const float4*)b)[tid];
  short4 o;
  o.x = f2bf((v.x - mean) * rsq * wv4.x + bv4.x);
  o.y = f2bf((v.y - mean) * rsq * wv4.y + bv4.y);
  o.z = f2bf((v.z - mean) * rsq * wv4.z + bv4.z);
  o.w = f2bf((v.w - mean) * rsq * wv4.w + bv4.w);
  ((short4*)(h1 + (size_t)row * HID))[tid] = o;
}

// ------- split-K bf16-partial merge + bias + residual -> fp32 out -------
__global__ __launch_bounds__(256) void merge_bias_kernel(
    const short* __restrict__ part, const float* __restrict__ bias,
    const float* __restrict__ resid, float* __restrict__ out) {
  int i = blockIdx.x * blockDim.x + threadIdx.x;
  int col4 = i & 255;
  float4 v = {0.f, 0.f, 0.f, 0.f};
#pragma unroll
  for (int z = 0; z < 4; z++) {
    uint2 p = ((const uint2*)(part + (size_t)z * SEQ * HID))[i];
    v.x += bf2f_lo(p.x); v.y += bf2f_hi(p.x);
    v.z += bf2f_lo(p.y); v.w += bf2f_hi(p.y);
  }
  float4 bi = ((const float4*)bias)[col4];
  float4 rs = ((const float4*)resid)[i];
  float4 o;
  o.x = v.x + bi.x + rs.x;
  o.y = v.y + bi.y + rs.y;
  o.z = v.z + bi.z + rs.z;
  o.w = v.w + bi.w + rs.w;
  ((float4*)out)[i] = o;
}

extern "C" void kernel_launch(void* const* d_in, const int* in_sizes, int n_in,
                              void* d_out, int out_size, void* d_ws, size_t ws_size,
                              hipStream_t stream) {
  const float* x      = (const float*)d_in[0];
  const float* ropec  = (const float*)d_in[1];
  const float* ropes  = (const float*)d_in[2];
  const float* n0w    = (const float*)d_in[3];
  const float* n0b    = (const float*)d_in[4];
  const float* n1w    = (const float*)d_in[5];
  const float* n1b    = (const float*)d_in[6];
  const float* wqkv_w = (const float*)d_in[7];
  const float* wqkv_b = (const float*)d_in[8];
  const float* wo_w   = (const float*)d_in[9];
  const float* wo_b   = (const float*)d_in[10];
  const float* up_w   = (const float*)d_in[11];
  const float* up_b   = (const float*)d_in[12];
  const float* down_w = (const float*)d_in[13];
  const float* down_b = (const float*)d_in[14];
  const int*   offs   = (const int*)d_in[15];
  float* out = (float*)d_out;

  char* base = (char*)d_ws;
  // ---- static layout, lifetime-aliased (peak ~88.6 MB) ----
  short* wqkv_bf = (short*)(base + 0);            //  6.3 MB, whole run
  short* wo_bf   = (short*)(base + 6291456);      //  2.1 MB, whole run
  short* up_bf   = (short*)(base + 8388608);      //  8.4 MB, whole run
  short* down_bf = (short*)(base + 16777216);     //  8.4 MB, whole run
  short* h0      = (short*)(base + 25165824);     //  4.2 MB, dead after qkv gemm
  short* qkv_bf  = (short*)(base + 29360128);     // 12.6 MB, dead after ropev
  short* Qh      = (short*)(base + 41943040);     //  4.2 MB, dead after attn
  short* Kh      = (short*)(base + 46137344);     //  4.2 MB, dead after attn
  short* Vt      = (short*)(base + 50331648);     //  4.2 MB, dead after attn
  short* Opart   = (short*)(base + 54525952);     // 16.8 MB, dead after attn_merge
  float* Lpart   = (float*)(base + 71303168);     //  0.5 MB
  short* attn    = (short*)(base + 71827456);     //  4.2 MB, dead after wo gemm
  float* x1      = (float*)(base + 76021760);     //  8.4 MB, live to end
  short* h1      = (short*)(base + 84410368);     //  4.2 MB, dead after up gemm
  short* wopart  = (short*)(base + 25165824);     // 16.8 MB -> 41.9 MB (h0..Vt dead)
  short* u       = (short*)(base + 25165824);     // 16.8 MB -> 41.9 MB
  short* dnpart  = (short*)(base + 41943040);     // 16.8 MB -> 58.7 MB (Qh..Opart dead)

  cvt_all_kernel<<<12288, 256, 0, stream>>>(wqkv_w, wo_w, up_w, down_w,
                                            wqkv_bf, wo_bf, up_bf, down_bf);
  ln_kernel<<<2048, 256, 0, stream>>>(x, n0w, n0b, h0);
  gemm_bt_kernel<3><<<dim3(24, 16), 256, 0, stream>>>(h0, wqkv_bf, wqkv_b, nullptr,
                                                      qkv_bf, 2048, 3072, 1024, 1024);
  ropev_kernel<<<dim3(32, 16), 256, 0, stream>>>(qkv_bf, ropec, ropes, Qh, Kh, Vt);
  attn_kernel<<<dim3(32, 16, 4), 256, 0, stream>>>(Qh, Kh, Vt, offs, Opart, Lpart);
  attn_merge_kernel<<<2048, 256, 0, stream>>>(Opart, Lpart, attn);
  gemm_bt_kernel<5><<<dim3(8, 16, 4), 256, 0, stream>>>(attn, wo_bf, nullptr, nullptr,
                                                        wopart, 2048, 1024, 256, 1024);
  merge_ln_kernel<<<2048, 256, 0, stream>>>(wopart, wo_b, x, n1w, n1b, x1, h1);
  gemm_bt_kernel<2><<<dim3(32, 16), 256, 0, stream>>>(h1, up_bf, up_b, nullptr,
                                                      u, 2048, 4096, 1024, 1024);
  gemm_bt_kernel<5><<<dim3(8, 16, 4), 256, 0, stream>>>(u, down_bf, nullptr, nullptr,
                                                        dnpart, 2048, 1024, 1024, 4096);
  merge_bias_kernel<<<2048, 256, 0, stream>>>(dnpart, down_b, x1, out);
}

// Round 13
// 270.882 us; speedup vs baseline: 1.2167x; 1.0630x over previous
//
#include <hip/hip_runtime.h>
#include <hip/hip_bf16.h>
#include <math.h>

#define SEQ 2048
#define HID 1024
#define NH 16
#define HD 64

using f32x4  = __attribute__((ext_vector_type(4))) float;
using bf16x8 = __attribute__((ext_vector_type(8))) short;

union U8 { unsigned int u[4]; bf16x8 v; short s[8]; };

__device__ __forceinline__ short f2bf(float f) {
  unsigned int x = __float_as_uint(f);
  unsigned int r = (x + 0x7fffu + ((x >> 16) & 1u)) >> 16;
  return (short)(r & 0xffffu);
}

__device__ __forceinline__ unsigned int pkbf(float a, float b) {
  return ((unsigned int)(unsigned short)f2bf(a)) |
         (((unsigned int)(unsigned short)f2bf(b)) << 16);
}

__device__ __forceinline__ float bf2f_lo(unsigned int u) {
  return __uint_as_float((u & 0xffffu) << 16);
}
__device__ __forceinline__ float bf2f_hi(unsigned int u) {
  return __uint_as_float(u & 0xffff0000u);
}

__device__ __forceinline__ float fast_exp2(float x) {
#if __has_builtin(__builtin_amdgcn_exp2f)
  return __builtin_amdgcn_exp2f(x);
#else
  return exp2f(x);
#endif
}

__device__ __forceinline__ float fast_rcp(float x) {
#if __has_builtin(__builtin_amdgcn_rcpf)
  return __builtin_amdgcn_rcpf(x);
#else
  return 1.0f / x;
#endif
}

__device__ __forceinline__ void async_cp16(const void* g, void* l) {
  __builtin_amdgcn_global_load_lds(
      (__attribute__((address_space(1))) void*)(g),
      (__attribute__((address_space(3))) void*)(l), 16, 0, 0);
}

// ------------- fp32 -> bf16 conversion, all 4 weights in one launch ----------
__global__ void cvt_all_kernel(const float* __restrict__ a, const float* __restrict__ b,
                               const float* __restrict__ c, const float* __restrict__ d,
                               short* __restrict__ oa, short* __restrict__ ob,
                               short* __restrict__ oc, short* __restrict__ od) {
  int i = blockIdx.x * blockDim.x + threadIdx.x;  // float4 index, 3145728 total
  const float* src; short* dst; int off;
  if (i < 786432)        { src = a; dst = oa; off = i; }
  else if (i < 1048576)  { src = b; dst = ob; off = i - 786432; }
  else if (i < 2097152)  { src = c; dst = oc; off = i - 1048576; }
  else                   { src = d; dst = od; off = i - 2097152; }
  float4 v = ((const float4*)src)[off];
  short4 o;
  o.x = f2bf(v.x); o.y = f2bf(v.y); o.z = f2bf(v.z); o.w = f2bf(v.w);
  ((short4*)dst)[off] = o;
}

// ---------------- LayerNorm (row per block) ----------------
__global__ __launch_bounds__(256) void ln_kernel(const float* __restrict__ x,
    const float* __restrict__ w, const float* __restrict__ b, short* __restrict__ out) {
  int row = blockIdx.x;
  int tid = threadIdx.x;
  float4 v = ((const float4*)(x + (size_t)row * HID))[tid];
  float s  = v.x + v.y + v.z + v.w;
  float s2 = v.x*v.x + v.y*v.y + v.z*v.z + v.w*v.w;
#pragma unroll
  for (int o = 32; o >= 1; o >>= 1) {
    s  += __shfl_xor(s,  o);
    s2 += __shfl_xor(s2, o);
  }
  __shared__ float red[8];
  int wv = tid >> 6;
  if ((tid & 63) == 0) { red[wv] = s; red[4 + wv] = s2; }
  __syncthreads();
  float ts  = red[0] + red[1] + red[2] + red[3];
  float ts2 = red[4] + red[5] + red[6] + red[7];
  float mean = ts * (1.0f / HID);
  float var  = ts2 * (1.0f / HID) - mean * mean;
  float rs = rsqrtf(var + 1e-5f);
  float4 wv4 = ((const float4*)w)[tid];
  float4 bv4 = ((const float4*)b)[tid];
  short4 o;
  o.x = f2bf((v.x - mean) * rs * wv4.x + bv4.x);
  o.y = f2bf((v.y - mean) * rs * wv4.y + bv4.y);
  o.z = f2bf((v.z - mean) * rs * wv4.z + bv4.z);
  o.w = f2bf((v.w - mean) * rs * wv4.w + bv4.w);
  ((short4*)(out + (size_t)row * HID))[tid] = o;
}

// ---- Fused RoPE(q,k) + V-transpose, per (s0-block of 64, head) ----
__global__ __launch_bounds__(256) void ropev_kernel(const short* __restrict__ qkvb,
    const float* __restrict__ cosb, const float* __restrict__ sinb,
    short* __restrict__ Qh, short* __restrict__ Kh, short* __restrict__ Vt) {
  __shared__ short tile[64 * 72];
  int s0   = blockIdx.x * 64;
  int head = blockIdx.y;
  int tid  = threadIdx.x;
#pragma unroll
  for (int p = 0; p < 2; p++) {
    int seg = p * 256 + tid;
    int row = seg >> 3;
    int c8  = seg & 7;
    bf16x8 v = *(const bf16x8*)(qkvb + (size_t)(s0 + row) * 3072 + 2048 + head * 64 + c8 * 8);
    *(bf16x8*)(tile + row * 72 + c8 * 8) = v;
  }
  int sl = tid >> 3;
  int c  = tid & 7;
#pragma unroll
  for (int j = 0; j < 2; j++) {        // 0 = q, 1 = k
    float scale = (j == 0) ? 0.18033688011112043f : 1.0f;  // 0.125*log2(e)
    short* dstm = (j == 0) ? Qh : Kh;
#pragma unroll
    for (int half = 0; half < 2; half++) {
      int s = s0 + half * 32 + sl;
      uint4 uu = *(const uint4*)(qkvb + (size_t)s * 3072 + j * 1024 + head * 64 + c * 8);
      float4 cs = *(const float4*)(cosb + s * 32 + c * 4);
      float4 sn = *(const float4*)(sinb + s * 32 + c * 4);
      uint4 oo;
      {
        float a = bf2f_lo(uu.x), b = bf2f_hi(uu.x);
        oo.x = pkbf(scale * (a * cs.x - b * sn.x), scale * (a * sn.x + b * cs.x));
        a = bf2f_lo(uu.y); b = bf2f_hi(uu.y);
        oo.y = pkbf(scale * (a * cs.y - b * sn.y), scale * (a * sn.y + b * cs.y));
        a = bf2f_lo(uu.z); b = bf2f_hi(uu.z);
        oo.z = pkbf(scale * (a * cs.z - b * sn.z), scale * (a * sn.z + b * cs.z));
        a = bf2f_lo(uu.w); b = bf2f_hi(uu.w);
        oo.w = pkbf(scale * (a * cs.w - b * sn.w), scale * (a * sn.w + b * cs.w));
      }
      *(uint4*)(dstm + ((size_t)head * SEQ + s) * HD + c * 8) = oo;
    }
  }
  __syncthreads();
#pragma unroll
  for (int p = 0; p < 2; p++) {
    int seg = p * 256 + tid;
    int d   = seg >> 3;
    int sc  = seg & 7;
    U8 o;
#pragma unroll
    for (int jj = 0; jj < 8; jj++) o.s[jj] = tile[(sc * 8 + jj) * 72 + d];
    *(bf16x8*)(Vt + ((size_t)head * HD + d) * SEQ + s0 + sc * 8) = o.v;
  }
}

// ---------------- GEMM: C(MxN) = A(MxK) * B(NxK)^T, bf16 MFMA, BK=64 -------
// LDS pitch 64 shorts, slot = chunk ^ (row&7) (bank-even, verified symbolically).
// EPI 2: gelu bf16, EPI 3: bias bf16, EPI 5: split-K bf16 partial
template <int EPI>
__global__ __launch_bounds__(256) void gemm_bt_kernel(
    const short* __restrict__ A, const short* __restrict__ B,
    const float* __restrict__ bias, const float* __restrict__ resid,
    void* __restrict__ outp, int M, int N, int Klen, int Kstride) {
  __shared__ __attribute__((aligned(16))) short Alds[128 * 64];
  __shared__ __attribute__((aligned(16))) short Blds[128 * 64];
  int tid = threadIdx.x;
  int w    = tid >> 6;
  int lane = tid & 63;
  int lcol  = lane & 15;
  int lhalf = lane >> 4;
  int m0 = blockIdx.y * 128;
  int n0 = blockIdx.x * 128;
  int z  = blockIdx.z;
  int wm = (w & 1) * 64;
  int wn = (w >> 1) * 64;

  // staging: 4 cp16 rounds per buffer; global chunk swizzled by row&7
  const short* apt[4];
  const short* bpt[4];
#pragma unroll
  for (int p = 0; p < 4; p++) {
    int seg = p * 256 + tid;
    int row = seg >> 3;
    int c   = (seg & 7) ^ (row & 7);
    apt[p] = A + (size_t)z * Klen + (size_t)(m0 + row) * Kstride + c * 8;
    bpt[p] = B + (size_t)z * Klen + (size_t)(n0 + row) * Kstride + c * 8;
  }

  f32x4 acc[4][4];
#pragma unroll
  for (int i = 0; i < 4; i++)
#pragma unroll
    for (int j = 0; j < 4; j++) acc[i][j] = (f32x4){0.f, 0.f, 0.f, 0.f};

  for (int k0 = 0; k0 < Klen; k0 += 64) {
#pragma unroll
    for (int p = 0; p < 4; p++) {
      async_cp16(apt[p], Alds + p * 2048 + w * 512);  apt[p] += 64;
      async_cp16(bpt[p], Blds + p * 2048 + w * 512);  bpt[p] += 64;
    }
    __syncthreads();
#pragma unroll
    for (int kc = 0; kc < 2; kc++) {
      bf16x8 af[4], bfr[4];
#pragma unroll
      for (int i = 0; i < 4; i++) {
        int row = wm + i * 16 + lcol;
        af[i] = *(const bf16x8*)(Alds + row * 64 + (((kc * 4 + lhalf) ^ (row & 7)) * 8));
      }
#pragma unroll
      for (int j = 0; j < 4; j++) {
        int row = wn + j * 16 + lcol;
        bfr[j] = *(const bf16x8*)(Blds + row * 64 + (((kc * 4 + lhalf) ^ (row & 7)) * 8));
      }
#pragma unroll
      for (int i = 0; i < 4; i++)
#pragma unroll
        for (int j = 0; j < 4; j++)
          acc[i][j] = __builtin_amdgcn_mfma_f32_16x16x32_bf16(af[i], bfr[j], acc[i][j], 0, 0, 0);
    }
    __syncthreads();
  }

#pragma unroll
  for (int i = 0; i < 4; i++) {
#pragma unroll
    for (int j = 0; j < 4; j++) {
#pragma unroll
      for (int r = 0; r < 4; r++) {
        int row = m0 + wm + i * 16 + lhalf * 4 + r;
        int col = n0 + wn + j * 16 + lcol;
        float v = acc[i][j][r];
        if (EPI != 5) v += bias[col];
        if (EPI == 2) {
          float t = v * (1.5957691216057308f + 0.07135481283942279f * v * v);
          float e = fast_exp2(t * -1.4426950408889634f);
          v = v * fast_rcp(1.0f + e);
          ((short*)outp)[(size_t)row * N + col] = f2bf(v);
        } else if (EPI == 3) {
          ((short*)outp)[(size_t)row * N + col] = f2bf(v);
        } else {  // EPI 5: bf16 partial
          ((short*)outp)[(size_t)z * M * N + (size_t)row * N + col] = f2bf(v);
        }
      }
    }
  }
}

// ---- Attention (R8-proven): 64 q/block, single per-wave Plds, z-split 4 ----
__global__ __launch_bounds__(256) void attn_kernel(
    const short* __restrict__ Qh, const short* __restrict__ Kh,
    const short* __restrict__ Vt, const int* __restrict__ offs,
    short* __restrict__ Opart, float* __restrict__ Lpart) {
  __shared__ __attribute__((aligned(16))) short Klds[64 * 64];
  __shared__ __attribute__((aligned(16))) short Vlds[64 * 64];
  __shared__ __attribute__((aligned(16))) unsigned int Plds[4][16 * 34];
  int head = blockIdx.y;
  int q0   = blockIdx.x * 64;
  int z    = blockIdx.z;
  int tid  = threadIdx.x;
  int w    = tid >> 6;
  int lane = tid & 63;
  int lcol = lane & 15;
  int h    = lane >> 4;
  int s7   = lcol & 7;
  int o1 = offs[1], o2 = offs[2], o3 = offs[3];

  int qrow = q0 + w * 16 + lcol;
  const short* qb = Qh + ((size_t)head * SEQ + qrow) * HD;
  bf16x8 qf0 = *(const bf16x8*)(qb + h * 8);
  bf16x8 qf1 = *(const bf16x8*)(qb + 32 + h * 8);
  int sq = (qrow >= o1) + (qrow >= o2) + (qrow >= o3);
  U8 qe;
  qe.u[0] = 0; qe.u[1] = 0; qe.u[2] = 0; qe.u[3] = 0;
  if (h == 0) qe.s[sq] = (short)0x3FB9;  // bf16(log2e)

  bf16x8 ones;
#pragma unroll
  for (int i = 0; i < 8; i++) ones[i] = 0x3F80;

  int kb0 = lcol * 64 + ((h ^ s7) * 8);
  int kb1 = lcol * 64 + (((4 + h) ^ s7) * 8);
  int vb0 = kb0, vb1 = kb1;
  int pwb = lcol * 34 + h * 2;
  int prb = lcol * 34 + h * 4;

  int tbeg = z * 512;
  const short* kp0; const short* kp1; const short* vp0; const short* vp1;
  {
    int seg = tid, row = seg >> 3, g = (seg & 7) ^ (row & 7);
    kp0 = Kh + ((size_t)head * SEQ + tbeg + row) * HD + g * 8;
    vp0 = Vt + ((size_t)head * HD + row) * SEQ + tbeg + g * 8;
    seg = 256 + tid; row = seg >> 3; g = (seg & 7) ^ (row & 7);
    kp1 = Kh + ((size_t)head * SEQ + tbeg + row) * HD + g * 8;
    vp1 = Vt + ((size_t)head * HD + row) * SEQ + tbeg + g * 8;
  }

  f32x4 o_acc[4];
#pragma unroll
  for (int nt = 0; nt < 4; nt++) o_acc[nt] = (f32x4){0.f, 0.f, 0.f, 0.f};
  f32x4 acc_l = (f32x4){0.f, 0.f, 0.f, 0.f};

  for (int t0 = 0; t0 < 512; t0 += 64) {
    async_cp16(kp0, Klds + w * 512);          kp0 += 64 * HD;
    async_cp16(kp1, Klds + 2048 + w * 512);   kp1 += 64 * HD;
    async_cp16(vp0, Vlds + w * 512);          vp0 += 64;
    async_cp16(vp1, Vlds + 2048 + w * 512);   vp1 += 64;
    __syncthreads();

#pragma unroll
    for (int n = 0; n < 4; n++) {
      bf16x8 kf0 = *(const bf16x8*)(Klds + n * 1024 + kb0);
      bf16x8 kf1 = *(const bf16x8*)(Klds + n * 1024 + kb1);
      int key = tbeg + t0 + n * 16 + lcol;
      int sk = (key >= o1) + (key >= o2) + (key >= o3);
      U8 ke;
      ke.u[0] = (h == 0) ? ((sk == 0) ? 0x00003F80u : (sk == 1) ? 0x3F800000u : 0u) : 0u;
      ke.u[1] = (h == 0) ? ((sk == 2) ? 0x00003F80u : (sk == 3) ? 0x3F800000u : 0u) : 0u;
      ke.u[2] = 0; ke.u[3] = 0;

      f32x4 sacc = (f32x4){0.f, 0.f, 0.f, 0.f};
      sacc = __builtin_amdgcn_mfma_f32_16x16x32_bf16(kf0, qf0, sacc, 0, 0, 0);
      sacc = __builtin_amdgcn_mfma_f32_16x16x32_bf16(kf1, qf1, sacc, 0, 0, 0);
      sacc = __builtin_amdgcn_mfma_f32_16x16x32_bf16(ke.v, qe.v, sacc, 0, 0, 0);

      float p0 = fast_exp2(sacc[0]);
      float p1 = fast_exp2(sacc[1]);
      float p2 = fast_exp2(sacc[2]);
      float p3 = fast_exp2(sacc[3]);
      uint2 pw;
      pw.x = __builtin_amdgcn_perm(__float_as_uint(p1), __float_as_uint(p0), 0x07060302);
      pw.y = __builtin_amdgcn_perm(__float_as_uint(p3), __float_as_uint(p2), 0x07060302);
      *(uint2*)&Plds[w][pwb + n * 8] = pw;
    }

#pragma unroll
    for (int kc = 0; kc < 2; kc++) {
      uint2 a = *(const uint2*)&Plds[w][prb + kc * 16];
      uint2 b = *(const uint2*)&Plds[w][prb + kc * 16 + 2];
      U8 pu;
      pu.u[0] = a.x; pu.u[1] = a.y; pu.u[2] = b.x; pu.u[3] = b.y;
      int vb = kc ? vb1 : vb0;
#pragma unroll
      for (int nt = 0; nt < 4; nt++) {
        bf16x8 vf = *(const bf16x8*)(Vlds + nt * 1024 + vb);
        o_acc[nt] = __builtin_amdgcn_mfma_f32_16x16x32_bf16(vf, pu.v, o_acc[nt], 0, 0, 0);
      }
      acc_l = __builtin_amdgcn_mfma_f32_16x16x32_bf16(ones, pu.v, acc_l, 0, 0, 0);
    }
    __syncthreads();
  }

  short* op = Opart + ((size_t)z * SEQ + qrow) * HID + head * HD + h * 4;
#pragma unroll
  for (int nt = 0; nt < 4; nt++) {
    uint2 ua;
    ua.x = pkbf(o_acc[nt][0], o_acc[nt][1]);
    ua.y = pkbf(o_acc[nt][2], o_acc[nt][3]);
    *(uint2*)(op + nt * 16) = ua;
  }
  if (lane < 16)
    Lpart[((size_t)z * NH + head) * SEQ + qrow] = acc_l[0];
}

// ---- merge 4 bf16 z-partials, normalize by sum(l), out bf16 ----
__global__ __launch_bounds__(256) void attn_merge_kernel(
    const short* __restrict__ Opart, const float* __restrict__ Lpart,
    short* __restrict__ attn) {
  int i = blockIdx.x * blockDim.x + threadIdx.x;
  int col4 = i & 255;
  int row  = i >> 8;
  int head = col4 >> 4;
  float acc0 = 0.f, acc1 = 0.f, acc2 = 0.f, acc3 = 0.f, l = 0.f;
#pragma unroll
  for (int zz = 0; zz < 4; zz++) {
    uint2 p = ((const uint2*)(Opart + (size_t)zz * SEQ * HID))[i];
    acc0 += bf2f_lo(p.x); acc1 += bf2f_hi(p.x);
    acc2 += bf2f_lo(p.y); acc3 += bf2f_hi(p.y);
    l += Lpart[((size_t)zz * NH + head) * SEQ + row];
  }
  float rl = fast_rcp(l);
  uint2 o;
  o.x = pkbf(acc0 * rl, acc1 * rl);
  o.y = pkbf(acc2 * rl, acc3 * rl);
  ((uint2*)attn)[i] = o;
}

// ------- split-K bf16-partial merge + bias + residual + LayerNorm -------
__global__ __launch_bounds__(256) void merge_ln_kernel(
    const short* __restrict__ part, const float* __restrict__ bias,
    const float* __restrict__ resid, const float* __restrict__ w,
    const float* __restrict__ b, float* __restrict__ x1, short* __restrict__ h1) {
  int row = blockIdx.x;
  int tid = threadIdx.x;
  size_t idx = (size_t)row * HID / 4 + tid;
  float4 v = {0.f, 0.f, 0.f, 0.f};
#pragma unroll
  for (int z = 0; z < 4; z++) {
    uint2 p = ((const uint2*)(part + (size_t)z * SEQ * HID))[idx];
    v.x += bf2f_lo(p.x); v.y += bf2f_hi(p.x);
    v.z += bf2f_lo(p.y); v.w += bf2f_hi(p.y);
  }
  float4 bi = ((const float4*)bias)[tid];
  float4 rs4 = ((const float4*)(resid + (size_t)row * HID))[tid];
  v.x += bi.x + rs4.x; v.y += bi.y + rs4.y; v.z += bi.z + rs4.z; v.w += bi.w + rs4.w;
  ((float4*)(x1 + (size_t)row * HID))[tid] = v;
  float s  = v.x + v.y + v.z + v.w;
  float s2 = v.x*v.x + v.y*v.y + v.z*v.z + v.w*v.w;
#pragma unroll
  for (int o = 32; o >= 1; o >>= 1) {
    s  += __shfl_xor(s,  o);
    s2 += __shfl_xor(s2, o);
  }
  __shared__ float red[8];
  int wv = tid >> 6;
  if ((tid & 63) == 0) { red[wv] = s; red[4 + wv] = s2; }
  __syncthreads();
  float ts  = red[0] + red[1] + red[2] + red[3];
  float ts2 = red[4] + red[5] + red[6] + red[7];
  float mean = ts * (1.0f / HID);
  float var  = ts2 * (1.0f / HID) - mean * mean;
  float rsq = rsqrtf(var + 1e-5f);
  float4 wv4 = ((const float4*)w)[tid];
  float4 bv4 = ((const float4*)b)[tid];
  short4 o;
  o.x = f2bf((v.x - mean) * rsq * wv4.x + bv4.x);
  o.y = f2bf((v.y - mean) * rsq * wv4.y + bv4.y);
  o.z = f2bf((v.z - mean) * rsq * wv4.z + bv4.z);
  o.w = f2bf((v.w - mean) * rsq * wv4.w + bv4.w);
  ((short4*)(h1 + (size_t)row * HID))[tid] = o;
}

// ------- split-K bf16-partial merge + bias + residual -> fp32 out -------
__global__ __launch_bounds__(256) void merge_bias_kernel(
    const short* __restrict__ part, const float* __restrict__ bias,
    const float* __restrict__ resid, float* __restrict__ out) {
  int i = blockIdx.x * blockDim.x + threadIdx.x;
  int col4 = i & 255;
  float4 v = {0.f, 0.f, 0.f, 0.f};
#pragma unroll
  for (int z = 0; z < 4; z++) {
    uint2 p = ((const uint2*)(part + (size_t)z * SEQ * HID))[i];
    v.x += bf2f_lo(p.x); v.y += bf2f_hi(p.x);
    v.z += bf2f_lo(p.y); v.w += bf2f_hi(p.y);
  }
  float4 bi = ((const float4*)bias)[col4];
  float4 rs = ((const float4*)resid)[i];
  float4 o;
  o.x = v.x + bi.x + rs.x;
  o.y = v.y + bi.y + rs.y;
  o.z = v.z + bi.z + rs.z;
  o.w = v.w + bi.w + rs.w;
  ((float4*)out)[i] = o;
}

extern "C" void kernel_launch(void* const* d_in, const int* in_sizes, int n_in,
                              void* d_out, int out_size, void* d_ws, size_t ws_size,
                              hipStream_t stream) {
  const float* x      = (const float*)d_in[0];
  const float* ropec  = (const float*)d_in[1];
  const float* ropes  = (const float*)d_in[2];
  const float* n0w    = (const float*)d_in[3];
  const float* n0b    = (const float*)d_in[4];
  const float* n1w    = (const float*)d_in[5];
  const float* n1b    = (const float*)d_in[6];
  const float* wqkv_w = (const float*)d_in[7];
  const float* wqkv_b = (const float*)d_in[8];
  const float* wo_w   = (const float*)d_in[9];
  const float* wo_b   = (const float*)d_in[10];
  const float* up_w   = (const float*)d_in[11];
  const float* up_b   = (const float*)d_in[12];
  const float* down_w = (const float*)d_in[13];
  const float* down_b = (const float*)d_in[14];
  const int*   offs   = (const int*)d_in[15];
  float* out = (float*)d_out;

  char* base = (char*)d_ws;
  // ---- static layout, lifetime-aliased (peak ~88.6 MB) ----
  short* wqkv_bf = (short*)(base + 0);            //  6.3 MB, whole run
  short* wo_bf   = (short*)(base + 6291456);      //  2.1 MB, whole run
  short* up_bf   = (short*)(base + 8388608);      //  8.4 MB, whole run
  short* down_bf = (short*)(base + 16777216);     //  8.4 MB, whole run
  short* h0      = (short*)(base + 25165824);     //  4.2 MB, dead after qkv gemm
  short* qkv_bf  = (short*)(base + 29360128);     // 12.6 MB, dead after ropev
  short* Qh      = (short*)(base + 41943040);     //  4.2 MB, dead after attn
  short* Kh      = (short*)(base + 46137344);     //  4.2 MB, dead after attn
  short* Vt      = (short*)(base + 50331648);     //  4.2 MB, dead after attn
  short* Opart   = (short*)(base + 54525952);     // 16.8 MB, dead after attn_merge
  float* Lpart   = (float*)(base + 71303168);     //  0.5 MB
  short* attn    = (short*)(base + 71827456);     //  4.2 MB, dead after wo gemm
  float* x1      = (float*)(base + 76021760);     //  8.4 MB, live to end
  short* h1      = (short*)(base + 84410368);     //  4.2 MB, dead after up gemm
  short* wopart  = (short*)(base + 25165824);     // 16.8 MB -> 41.9 MB (h0..Vt dead)
  short* u       = (short*)(base + 25165824);     // 16.8 MB -> 41.9 MB
  short* dnpart  = (short*)(base + 41943040);     // 16.8 MB -> 58.7 MB (Qh..Opart dead)

  cvt_all_kernel<<<12288, 256, 0, stream>>>(wqkv_w, wo_w, up_w, down_w,
                                            wqkv_bf, wo_bf, up_bf, down_bf);
  ln_kernel<<<2048, 256, 0, stream>>>(x, n0w, n0b, h0);
  gemm_bt_kernel<3><<<dim3(24, 16), 256, 0, stream>>>(h0, wqkv_bf, wqkv_b, nullptr,
                                                      qkv_bf, 2048, 3072, 1024, 1024);
  ropev_kernel<<<dim3(32, 16), 256, 0, stream>>>(qkv_bf, ropec, ropes, Qh, Kh, Vt);
  attn_kernel<<<dim3(32, 16, 4), 256, 0, stream>>>(Qh, Kh, Vt, offs, Opart, Lpart);
  attn_merge_kernel<<<2048, 256, 0, stream>>>(Opart, Lpart, attn);
  gemm_bt_kernel<5><<<dim3(8, 16, 4), 256, 0, stream>>>(attn, wo_bf, nullptr, nullptr,
                                                        wopart, 2048, 1024, 256, 1024);
  merge_ln_kernel<<<2048, 256, 0, stream>>>(wopart, wo_b, x, n1w, n1b, x1, h1);
  gemm_bt_kernel<2><<<dim3(32, 16), 256, 0, stream>>>(h1, up_bf, up_b, nullptr,
                                                      u, 2048, 4096, 1024, 1024);
  gemm_bt_kernel<5><<<dim3(8, 16, 4), 256, 0, stream>>>(u, down_bf, nullptr, nullptr,
                                                        dnpart, 2048, 1024, 1024, 4096);
  merge_bias_kernel<<<2048, 256, 0, stream>>>(dnpart, down_b, x1, out);
}